// Round 1
// baseline (407.141 us; speedup 1.0000x reference)
//
#include <hip/hip_runtime.h>
#include <math.h>

// ProjectionLayer: out[b,t,gx,gy] = data[b,t, argmin_n ||locs[b,n]*25+25 - (gx,gy)|| ]
// B=64, T=1024, N=256 sensors, G=50 (2500 grid cells).
// Stage 1 (nearest_k): 41M distance evals -> nearest[b,g] in d_ws (640 KB).
// Stage 2 (gather_k): 655 MB of coalesced float4 stores, gathered reads from
// 1KB-hot data rows (L1/L2 resident). HBM-write-bound, roofline ~115 us.

#define GRIDG 50
#define GG    2500   // GRIDG*GRIDG
#define GQ    625    // GG/4 (float4 groups per row)
#define NS    256    // sensors
#define TT    1024
#define BB    64
#define TCH   8      // t-chunks in gather
#define TPB   (TT / TCH)

// exact replication of reference fp32 arithmetic: unfused mul/add + rounded sqrt
__device__ __forceinline__ float ref_dist(float lx, float ly, float gx, float gy) {
    const float dx = lx - gx;
    const float dy = ly - gy;
    const float s  = __fadd_rn(__fmul_rn(dx, dx), __fmul_rn(dy, dy));
    return __fsqrt_rn(s);
}

// ---- Stage 1: nearest sensor index per grid cell -----------------------------
__global__ __launch_bounds__(256) void nearest_k(const float* __restrict__ locs,
                                                 int* __restrict__ nearest) {
    __shared__ float lsx[NS];
    __shared__ float lsy[NS];
    const int b   = blockIdx.x / 10;   // 10 blocks of 256 cover 2500 cells
    const int gc  = blockIdx.x % 10;
    const int tid = threadIdx.x;

    // load + scale locs[b] into LDS (reference: locs*25 + 25, unfused)
    const float2 l = ((const float2*)locs)[b * NS + tid];
    lsx[tid] = __fadd_rn(__fmul_rn(l.x, 25.0f), 25.0f);
    lsy[tid] = __fadd_rn(__fmul_rn(l.y, 25.0f), 25.0f);
    __syncthreads();

    const int g = gc * 256 + tid;
    if (g >= GG) return;
    const float gx = (float)(g / GRIDG);
    const float gy = (float)(g % GRIDG);

    float best = 1.0e30f;
    int   bi   = 0;
    #pragma unroll 4
    for (int n = 0; n < NS; ++n) {          // ascending n + strict '<'  => first-index
        const float d = ref_dist(lsx[n], lsy[n], gx, gy);   //    tie-break == jnp.argmin
        if (d < best) { best = d; bi = n; }
    }
    nearest[b * GG + g] = bi;
}

// ---- Stage 2: broadcast-gather over T ---------------------------------------
__global__ __launch_bounds__(256) void gather_k(const float* __restrict__ data,
                                                const int* __restrict__ nearest,
                                                float* __restrict__ out) {
    const int b  = blockIdx.z;
    const int gq = blockIdx.x * 256 + threadIdx.x;   // float4 group in [0,625)
    if (gq >= GQ) return;
    const int t0 = blockIdx.y * TPB;

    // 4 gather indices for this thread's 4 consecutive grid cells
    const int4 iv = ((const int4*)nearest)[b * GQ + gq];

    const float* __restrict__ dbase = data + (size_t)b * TT * NS;
    float4*      __restrict__ obase = (float4*)out + (size_t)b * TT * GQ + gq;

    #pragma unroll 4
    for (int t = t0; t < t0 + TPB; ++t) {
        const float* __restrict__ row = dbase + t * NS;   // 1KB row, cache-hot
        float4 v;
        v.x = row[iv.x];
        v.y = row[iv.y];
        v.z = row[iv.z];
        v.w = row[iv.w];
        obase[(size_t)t * GQ] = v;                        // coalesced 16B/lane store
    }
}

// ---- Fallback: fused (only if ws too small for the 640 KB index buffer) -----
__global__ __launch_bounds__(256) void fused_k(const float* __restrict__ data,
                                               const float* __restrict__ locs,
                                               float* __restrict__ out) {
    __shared__ float lsx[NS];
    __shared__ float lsy[NS];
    const int b   = blockIdx.z;
    const int tid = threadIdx.x;
    const float2 l = ((const float2*)locs)[b * NS + tid];
    lsx[tid] = __fadd_rn(__fmul_rn(l.x, 25.0f), 25.0f);
    lsy[tid] = __fadd_rn(__fmul_rn(l.y, 25.0f), 25.0f);
    __syncthreads();

    const int gq = blockIdx.x * 256 + tid;
    if (gq >= GQ) return;

    int iv[4];
    #pragma unroll
    for (int k = 0; k < 4; ++k) {
        const int g  = gq * 4 + k;
        const float gx = (float)(g / GRIDG);
        const float gy = (float)(g % GRIDG);
        float best = 1.0e30f;
        int   bi   = 0;
        for (int n = 0; n < NS; ++n) {
            const float d = ref_dist(lsx[n], lsy[n], gx, gy);
            if (d < best) { best = d; bi = n; }
        }
        iv[k] = bi;
    }

    const int t0 = blockIdx.y * (TT / 2);
    const float* __restrict__ dbase = data + (size_t)b * TT * NS;
    float4*      __restrict__ obase = (float4*)out + (size_t)b * TT * GQ + gq;
    #pragma unroll 4
    for (int t = t0; t < t0 + TT / 2; ++t) {
        const float* __restrict__ row = dbase + t * NS;
        float4 v;
        v.x = row[iv[0]];
        v.y = row[iv[1]];
        v.z = row[iv[2]];
        v.w = row[iv[3]];
        obase[(size_t)t * GQ] = v;
    }
}

extern "C" void kernel_launch(void* const* d_in, const int* in_sizes, int n_in,
                              void* d_out, int out_size, void* d_ws, size_t ws_size,
                              hipStream_t stream) {
    const float* data = (const float*)d_in[0];   // [64,1024,256] f32
    const float* locs = (const float*)d_in[1];   // [64,256,2]    f32
    float*       out  = (float*)d_out;           // [64,1024,50,50] f32
    (void)in_sizes; (void)n_in; (void)out_size;

    const size_t idx_bytes = (size_t)BB * GG * sizeof(int);   // 640 KB
    if (ws_size >= idx_bytes) {
        int* nearest = (int*)d_ws;
        nearest_k<<<dim3(BB * 10), 256, 0, stream>>>(locs, nearest);
        gather_k<<<dim3(3, TCH, BB), 256, 0, stream>>>(data, nearest, out);
    } else {
        fused_k<<<dim3(3, 2, BB), 256, 0, stream>>>(data, locs, out);
    }
}

// Round 2
// 199.961 us; speedup vs baseline: 2.0361x; 2.0361x over previous
//
#include <hip/hip_runtime.h>
#include <math.h>

// ProjectionLayer: out[b,t,gx,gy] = data[b,t, argmin_n ||locs[b,n]*25+25 - (gx,gy)|| ]
// B=64, T=1024, N=256 sensors, G=50 (2500 grid cells).
// Stage 1 (nearest_k): 41M distance evals -> nearest[b,g] in d_ws (640 KB).
// Stage 2 (gather_lds_k): stage 16 data rows in LDS per sync, gather via
// ds_read_b32 (random scatter is cheap in LDS, ~2-way avg bank alias), write
// 655 MB coalesced float4. HBM-write-bound, roofline ~110 us.
// R1 lesson: per-lane scattered GLOBAL loads cost ~1 lane/cycle in the TA
// (~330 us) even when L1-resident -- scatter must go through LDS.

#define GRIDG  50
#define GG     2500   // GRIDG*GRIDG
#define GQ     625    // GG/4 (float4 groups per output row)
#define NS     256    // sensors
#define TT     1024
#define BB     64
#define TCHUNK 64     // t rows per block
#define RSTG   16     // rows staged in LDS per barrier (16 KB)

// exact replication of reference fp32 arithmetic: unfused mul/add + rounded sqrt
__device__ __forceinline__ float ref_dist(float lx, float ly, float gx, float gy) {
    const float dx = lx - gx;
    const float dy = ly - gy;
    const float s  = __fadd_rn(__fmul_rn(dx, dx), __fmul_rn(dy, dy));
    return __fsqrt_rn(s);
}

// ---- Stage 1: nearest sensor index per grid cell -----------------------------
__global__ __launch_bounds__(256) void nearest_k(const float* __restrict__ locs,
                                                 int* __restrict__ nearest) {
    __shared__ float lsx[NS];
    __shared__ float lsy[NS];
    const int b   = blockIdx.x / 10;   // 10 blocks of 256 cover 2500 cells
    const int gc  = blockIdx.x % 10;
    const int tid = threadIdx.x;

    const float2 l = ((const float2*)locs)[b * NS + tid];
    lsx[tid] = __fadd_rn(__fmul_rn(l.x, 25.0f), 25.0f);
    lsy[tid] = __fadd_rn(__fmul_rn(l.y, 25.0f), 25.0f);
    __syncthreads();

    const int g = gc * 256 + tid;
    if (g >= GG) return;
    const float gx = (float)(g / GRIDG);
    const float gy = (float)(g % GRIDG);

    float best = 1.0e30f;
    int   bi   = 0;
    #pragma unroll 4
    for (int n = 0; n < NS; ++n) {          // ascending n + strict '<'  => first-index
        const float d = ref_dist(lsx[n], lsy[n], gx, gy);   //    tie-break == jnp.argmin
        if (d < best) { best = d; bi = n; }
    }
    nearest[b * GG + g] = bi;
}

// ---- Stage 2: LDS-staged broadcast-gather over T ----------------------------
__global__ __launch_bounds__(256) void gather_lds_k(const float* __restrict__ data,
                                                    const int* __restrict__ nearest,
                                                    float* __restrict__ out) {
    __shared__ float rows[RSTG * NS];   // 16 KB
    const int tid = threadIdx.x;
    const int b   = blockIdx.y;
    const int t0  = blockIdx.x * TCHUNK;

    // per-thread gather indices (loop-invariant over t) -> registers
    int4 iv[3];
    #pragma unroll
    for (int j = 0; j < 3; ++j) {
        const int gq = tid + j * 256;
        iv[j] = (gq < GQ) ? ((const int4*)nearest)[b * GQ + gq]
                          : make_int4(0, 0, 0, 0);
    }

    const float4* __restrict__ dbase = (const float4*)data + (size_t)b * TT * (NS / 4);
    float4*       __restrict__ obase = (float4*)out + (size_t)b * TT * GQ;

    for (int ts = t0; ts < t0 + TCHUNK; ts += RSTG) {
        __syncthreads();   // all waves done reading previous stage
        // stage RSTG rows = RSTG*NS/4 = 1024 float4 = 4 per thread, coalesced
        const float4* __restrict__ src = dbase + (size_t)ts * (NS / 4);
        #pragma unroll
        for (int i = 0; i < (RSTG * NS / 4) / 256; ++i) {
            const int f = i * 256 + tid;
            ((float4*)rows)[f] = src[f];
        }
        __syncthreads();

        #pragma unroll 4
        for (int r = 0; r < RSTG; ++r) {
            const float* __restrict__ row  = rows + r * NS;
            float4*      __restrict__ orow = obase + (size_t)(ts + r) * GQ;
            #pragma unroll
            for (int j = 0; j < 3; ++j) {
                const int gq = tid + j * 256;
                if (gq < GQ) {
                    float4 v;
                    v.x = row[iv[j].x];
                    v.y = row[iv[j].y];
                    v.z = row[iv[j].z];
                    v.w = row[iv[j].w];
                    orow[gq] = v;          // coalesced 16B/lane store
                }
            }
        }
    }
}

// ---- Fallback: fused (only if ws too small for the 640 KB index buffer) -----
__global__ __launch_bounds__(256) void fused_k(const float* __restrict__ data,
                                               const float* __restrict__ locs,
                                               float* __restrict__ out) {
    __shared__ float lsx[NS];
    __shared__ float lsy[NS];
    const int b   = blockIdx.z;
    const int tid = threadIdx.x;
    const float2 l = ((const float2*)locs)[b * NS + tid];
    lsx[tid] = __fadd_rn(__fmul_rn(l.x, 25.0f), 25.0f);
    lsy[tid] = __fadd_rn(__fmul_rn(l.y, 25.0f), 25.0f);
    __syncthreads();

    const int gq = blockIdx.x * 256 + tid;
    if (gq >= GQ) return;

    int iv[4];
    #pragma unroll
    for (int k = 0; k < 4; ++k) {
        const int g  = gq * 4 + k;
        const float gx = (float)(g / GRIDG);
        const float gy = (float)(g % GRIDG);
        float best = 1.0e30f;
        int   bi   = 0;
        for (int n = 0; n < NS; ++n) {
            const float d = ref_dist(lsx[n], lsy[n], gx, gy);
            if (d < best) { best = d; bi = n; }
        }
        iv[k] = bi;
    }

    const int t0 = blockIdx.y * (TT / 2);
    const float* __restrict__ dbase = data + (size_t)b * TT * NS;
    float4*      __restrict__ obase = (float4*)out + (size_t)b * TT * GQ + gq;
    #pragma unroll 4
    for (int t = t0; t < t0 + TT / 2; ++t) {
        const float* __restrict__ row = dbase + t * NS;
        float4 v;
        v.x = row[iv[0]];
        v.y = row[iv[1]];
        v.z = row[iv[2]];
        v.w = row[iv[3]];
        obase[(size_t)t * GQ] = v;
    }
}

extern "C" void kernel_launch(void* const* d_in, const int* in_sizes, int n_in,
                              void* d_out, int out_size, void* d_ws, size_t ws_size,
                              hipStream_t stream) {
    const float* data = (const float*)d_in[0];   // [64,1024,256] f32
    const float* locs = (const float*)d_in[1];   // [64,256,2]    f32
    float*       out  = (float*)d_out;           // [64,1024,50,50] f32
    (void)in_sizes; (void)n_in; (void)out_size;

    const size_t idx_bytes = (size_t)BB * GG * sizeof(int);   // 640 KB
    if (ws_size >= idx_bytes) {
        int* nearest = (int*)d_ws;
        nearest_k<<<dim3(BB * 10), 256, 0, stream>>>(locs, nearest);
        gather_lds_k<<<dim3(TT / TCHUNK, BB), 256, 0, stream>>>(data, nearest, out);
    } else {
        fused_k<<<dim3(3, 2, BB), 256, 0, stream>>>(data, locs, out);
    }
}